// Round 2
// baseline (42.114 us; speedup 1.0000x reference)
//
#include <hip/hip_runtime.h>
#include <math.h>

constexpr int SEQ = 8192;
constexpr int HID = 16;
constexpr int BLK = 128;            // threads per block (2 waves)
constexpr int NBLK = SEQ / BLK;     // 64 blocks
constexpr int WS_STRIDE = 48;       // per-block partial: 16 A + 16 B + 1 Vtot (padded)

__device__ __forceinline__ void load_row(const float* __restrict__ x, int r, float* f) {
    const float4* p = (const float4*)(x + (size_t)r * HID);
    float4 a = p[0], b = p[1], c = p[2], d = p[3];
    f[0]=a.x; f[1]=a.y; f[2]=a.z;  f[3]=a.w;
    f[4]=b.x; f[5]=b.y; f[6]=b.z;  f[7]=b.w;
    f[8]=c.x; f[9]=c.y; f[10]=c.z; f[11]=c.w;
    f[12]=d.x; f[13]=d.y; f[14]=d.z; f[15]=d.w;
}

__global__ __launch_bounds__(BLK) void satformer_fused(
    const float* __restrict__ x,
    const float* __restrict__ Wq, const float* __restrict__ bq,
    const float* __restrict__ Wk, const float* __restrict__ bk,
    const float* __restrict__ Wv, const float* __restrict__ bv,
    const int* __restrict__ heads_p,
    float* __restrict__ part,
    unsigned int* __restrict__ ticket,
    float* __restrict__ out)
{
    __shared__ float sWq[256];
    __shared__ float sWk[256];
    __shared__ float swv[16];     // column sums of Wv: swv[h] = sum_d Wv[d][h]
    __shared__ float sbq[16];
    __shared__ float sbk[16];
    __shared__ float sbv;         // sum of bv
    __shared__ float sK[BLK + 2][17];   // K rows r0-1 .. r0+BLK, padded (+1) -> 2-way alias only
    __shared__ float sVr[BLK + 2];      // V row-sums for same rows
    __shared__ float redA[2][16];
    __shared__ float redB[2][16];
    __shared__ float redV[2];
    __shared__ unsigned int isLast;

    const int tid = threadIdx.x;
    const int r0  = blockIdx.x * BLK;

    for (int i = tid; i < 256; i += BLK) { sWq[i] = Wq[i]; sWk[i] = Wk[i]; }
    if (tid < 16) {
        float acc = 0.f;
        #pragma unroll
        for (int d = 0; d < 16; ++d) acc += Wv[d * 16 + tid];
        swv[tid] = acc;
        sbq[tid] = bq[tid];
        sbk[tid] = bk[tid];
    }
    if (tid == BLK - 1) {
        float acc = 0.f;
        #pragma unroll
        for (int d = 0; d < 16; ++d) acc += bv[d];
        sbv = acc;
    }
    __syncthreads();

    // scaling = (HID/heads)^-0.5 ; heads=4 -> exactly 0.5
    const float scaling = rsqrtf((float)(HID / heads_p[0]));

    const int s = r0 + tid;
    float xs[16];
    load_row(x, s, xs);

    // Own row's K vector and V row-sum into LDS
    #pragma unroll
    for (int d = 0; d < 16; ++d) {
        float acc = sbk[d];
        #pragma unroll
        for (int h = 0; h < 16; ++h) acc += xs[h] * sWk[d * 16 + h];
        sK[tid + 1][d] = acc;
    }
    {
        float acc = sbv;
        #pragma unroll
        for (int h = 0; h < 16; ++h) acc += xs[h] * swv[h];
        sVr[tid + 1] = acc;
    }

    // Boundary rows (r0-1 and r0+BLK) handled by edge threads
    auto fill = [&](int row, int slot) {
        float xr[16];
        load_row(x, row, xr);
        #pragma unroll
        for (int d = 0; d < 16; ++d) {
            float acc = sbk[d];
            #pragma unroll
            for (int h = 0; h < 16; ++h) acc += xr[h] * sWk[d * 16 + h];
            sK[slot][d] = acc;
        }
        float acc = sbv;
        #pragma unroll
        for (int h = 0; h < 16; ++h) acc += xr[h] * swv[h];
        sVr[slot] = acc;
    };
    if (tid == 0 && r0 > 0)                 fill(r0 - 1, 0);
    if (tid == BLK - 1 && r0 + BLK < SEQ)   fill(r0 + BLK, BLK + 1);

    // Q for own row (registers)
    float q[16];
    #pragma unroll
    for (int d = 0; d < 16; ++d) {
        float acc = sbq[d];
        #pragma unroll
        for (int h = 0; h < 16; ++h) acc += xs[h] * sWq[d * 16 + h];
        q[d] = acc;
    }
    __syncthreads();

    // Band: j in {s-1, s, s+1} ∩ [0, SEQ)
    float denom = 0.f, num = 0.f;
    int nb = 0;
    #pragma unroll
    for (int off = -1; off <= 1; ++off) {
        int j = s + off;
        if (j < 0 || j >= SEQ) continue;
        int li = tid + 1 + off;
        float sc = 0.f;
        #pragma unroll
        for (int d = 0; d < 16; ++d) sc += q[d] * sK[li][d];
        sc *= scaling;
        float e = expf(sc);
        denom += e;
        num   += (e - 1.f) * sVr[li];
        ++nb;
    }
    denom += (float)(SEQ - nb);   // the (S-nb) off-band exp(0)=1 terms

    float a  = num / denom;       // per-row A contribution
    float b  = 1.f / denom;       // per-row B contribution
    float v  = sVr[tid + 1];      // per-row Vtot contribution

    // Bucket c = s & 15 == tid & 15. xor-16/32 folds preserve the bucket.
    float av = a, bb = b, vv = v;
    av += __shfl_xor(av, 16); av += __shfl_xor(av, 32);
    bb += __shfl_xor(bb, 16); bb += __shfl_xor(bb, 32);
    #pragma unroll
    for (int m = 1; m <= 32; m <<= 1) vv += __shfl_xor(vv, m);

    const int wave = tid >> 6;
    const int lane = tid & 63;
    if (lane < 16) { redA[wave][lane] = av; redB[wave][lane] = bb; }
    if (lane == 0) redV[wave] = vv;
    __syncthreads();

    if (tid < 16) {
        part[blockIdx.x * WS_STRIDE + tid]      = redA[0][tid] + redA[1][tid];
        part[blockIdx.x * WS_STRIDE + 16 + tid] = redB[0][tid] + redB[1][tid];
    }
    if (tid == 16) {
        part[blockIdx.x * WS_STRIDE + 32] = redV[0] + redV[1];
    }

    // ---- last-block-done finish (single launch, no second kernel) ----
    __threadfence();   // release: make this block's partials device-visible
    if (tid == 0) {
        unsigned int old = atomicAdd(ticket, 1u);
        // Works for ANY initial counter value (0xAA poison included): each call
        // advances the counter by exactly NBLK, so residue NBLK-1 (mod NBLK)
        // is seen by exactly one block per call.
        isLast = ((old & (NBLK - 1)) == (unsigned)(NBLK - 1)) ? 1u : 0u;
    }
    __syncthreads();

    if (isLast) {
        __threadfence();   // acquire: see all other blocks' partials
        const volatile float* vp = part;
        const int j = tid;           // 0..127
        const int c = j >> 3;        // output bin j reads pooled column j/8
        float A = 0.f, B = 0.f, V = 0.f;
        for (int k = 0; k < NBLK; ++k) {
            A += vp[k * WS_STRIDE + c];
            B += vp[k * WS_STRIDE + 16 + c];
            V += vp[k * WS_STRIDE + 32];
        }
        out[j] = (A + V * B) / (float)SEQ;
    }
}

extern "C" void kernel_launch(void* const* d_in, const int* in_sizes, int n_in,
                              void* d_out, int out_size, void* d_ws, size_t ws_size,
                              hipStream_t stream) {
    const float* x     = (const float*)d_in[0];
    const float* Wq    = (const float*)d_in[1];
    const float* bq    = (const float*)d_in[2];
    const float* Wk    = (const float*)d_in[3];
    const float* bk    = (const float*)d_in[4];
    const float* Wv    = (const float*)d_in[5];
    const float* bv    = (const float*)d_in[6];
    const int*   heads = (const int*)d_in[7];
    float*        part   = (float*)d_ws;                          // 64*48*4 = 12 KiB
    unsigned int* ticket = (unsigned int*)((char*)d_ws + NBLK * WS_STRIDE * sizeof(float));
    float*        out    = (float*)d_out;

    hipLaunchKernelGGL(satformer_fused, dim3(NBLK), dim3(BLK), 0, stream,
                       x, Wq, bq, Wk, bk, Wv, bv, heads, part, ticket, out);
}

// Round 6
// 17.170 us; speedup vs baseline: 2.4528x; 2.4528x over previous
//
#include <hip/hip_runtime.h>
#include <math.h>

constexpr int SEQ = 8192;
constexpr int HID = 16;
constexpr int BLK = 128;            // threads per block (2 waves)
constexpr int NBLK = SEQ / BLK;     // 64 blocks
constexpr int SLOTS = 33;           // per-block partial: 16 A + 16 B + 1 Vtot
constexpr unsigned int MAGIC = 0x5EEDF00Du;
constexpr int SPIN_BOUND = 1 << 22;

__device__ __forceinline__ void load_row(const float* __restrict__ x, int r, float* f) {
    const float4* p = (const float4*)(x + (size_t)r * HID);
    float4 a = p[0], b = p[1], c = p[2], d = p[3];
    f[0]=a.x; f[1]=a.y; f[2]=a.z;  f[3]=a.w;
    f[4]=b.x; f[5]=b.y; f[6]=b.z;  f[7]=b.w;
    f[8]=c.x; f[9]=c.y; f[10]=c.z; f[11]=c.w;
    f[12]=d.x; f[13]=d.y; f[14]=d.z; f[15]=d.w;
}

__global__ __launch_bounds__(BLK) void satformer_fused(
    const float* __restrict__ x,
    const float* __restrict__ Wq, const float* __restrict__ bq,
    const float* __restrict__ Wk, const float* __restrict__ bk,
    const float* __restrict__ Wv, const float* __restrict__ bv,
    const int* __restrict__ heads_p,
    unsigned int* __restrict__ part_u,   // [NBLK*SLOTS] float bit-patterns (k=0 unused)
    unsigned int* __restrict__ flags,    // [NBLK] per-block done flags (k=0 unused)
    float* __restrict__ out)
{
    __shared__ float sWq[256];
    __shared__ float sWk[256];
    __shared__ float swv[16];     // column sums of Wv
    __shared__ float sbq[16];
    __shared__ float sbk[16];
    __shared__ float sbv;         // sum of bv
    __shared__ float sK[BLK + 2][17];
    __shared__ float sVr[BLK + 2];
    __shared__ float redA[2][16];
    __shared__ float redB[2][16];
    __shared__ float redV[2];
    __shared__ float stage[(NBLK - 1) * SLOTS];   // block-0 only: others' partials

    const int tid = threadIdx.x;
    const int bid = blockIdx.x;
    const int r0  = bid * BLK;

    for (int i = tid; i < 256; i += BLK) { sWq[i] = Wq[i]; sWk[i] = Wk[i]; }
    if (tid < 16) {
        float acc = 0.f;
        #pragma unroll
        for (int d = 0; d < 16; ++d) acc += Wv[d * 16 + tid];
        swv[tid] = acc;
        sbq[tid] = bq[tid];
        sbk[tid] = bk[tid];
    }
    if (tid == BLK - 1) {
        float acc = 0.f;
        #pragma unroll
        for (int d = 0; d < 16; ++d) acc += bv[d];
        sbv = acc;
    }
    __syncthreads();

    // scaling = (HID/heads)^-0.5 ; heads=4 -> exactly 0.5
    const float scaling = rsqrtf((float)(HID / heads_p[0]));

    const int s = r0 + tid;
    float xs[16];
    load_row(x, s, xs);

    // Own row's K vector and V row-sum into LDS
    #pragma unroll
    for (int d = 0; d < 16; ++d) {
        float acc = sbk[d];
        #pragma unroll
        for (int h = 0; h < 16; ++h) acc += xs[h] * sWk[d * 16 + h];
        sK[tid + 1][d] = acc;
    }
    {
        float acc = sbv;
        #pragma unroll
        for (int h = 0; h < 16; ++h) acc += xs[h] * swv[h];
        sVr[tid + 1] = acc;
    }

    // Boundary rows handled by edge threads
    auto fill = [&](int row, int slot) {
        float xr[16];
        load_row(x, row, xr);
        #pragma unroll
        for (int d = 0; d < 16; ++d) {
            float acc = sbk[d];
            #pragma unroll
            for (int h = 0; h < 16; ++h) acc += xr[h] * sWk[d * 16 + h];
            sK[slot][d] = acc;
        }
        float acc = sbv;
        #pragma unroll
        for (int h = 0; h < 16; ++h) acc += xr[h] * swv[h];
        sVr[slot] = acc;
    };
    if (tid == 0 && r0 > 0)                 fill(r0 - 1, 0);
    if (tid == BLK - 1 && r0 + BLK < SEQ)   fill(r0 + BLK, BLK + 1);

    // Q for own row
    float q[16];
    #pragma unroll
    for (int d = 0; d < 16; ++d) {
        float acc = sbq[d];
        #pragma unroll
        for (int h = 0; h < 16; ++h) acc += xs[h] * sWq[d * 16 + h];
        q[d] = acc;
    }
    __syncthreads();

    // Band: j in {s-1, s, s+1} ∩ [0, SEQ)
    float denom = 0.f, num = 0.f;
    int nb = 0;
    #pragma unroll
    for (int off = -1; off <= 1; ++off) {
        int j = s + off;
        if (j < 0 || j >= SEQ) continue;
        int li = tid + 1 + off;
        float sc = 0.f;
        #pragma unroll
        for (int d = 0; d < 16; ++d) sc += q[d] * sK[li][d];
        sc *= scaling;
        float e = expf(sc);
        denom += e;
        num   += (e - 1.f) * sVr[li];
        ++nb;
    }
    denom += (float)(SEQ - nb);   // (S-nb) off-band exp(0)=1 terms

    float a = num / denom;
    float b = 1.f / denom;
    float v = sVr[tid + 1];

    // Bucket c = s & 15 == tid & 15; xor-16/32 folds preserve the bucket.
    float av = a, bb = b, vv = v;
    av += __shfl_xor(av, 16); av += __shfl_xor(av, 32);
    bb += __shfl_xor(bb, 16); bb += __shfl_xor(bb, 32);
    #pragma unroll
    for (int m = 1; m <= 32; m <<= 1) vv += __shfl_xor(vv, m);

    const int wave = tid >> 6;
    const int lane = tid & 63;
    if (lane < 16) { redA[wave][lane] = av; redB[wave][lane] = bb; }
    if (lane == 0) redV[wave] = vv;
    __syncthreads();

    if (bid != 0) {
        // ---- publish: SYSTEM-scope exchanges (sc0+sc1, performed past L2 at
        //      the device coherence point). Returns consumed; vmcnt(0) drains
        //      them before the flag exchange in the same wave.
        const int base = bid * SLOTS;
        if (tid < 16) {
            unsigned int o0 = __hip_atomic_exchange(&part_u[base + tid],
                __float_as_uint(redA[0][tid] + redA[1][tid]),
                __ATOMIC_RELAXED, __HIP_MEMORY_SCOPE_SYSTEM);
            unsigned int o1 = __hip_atomic_exchange(&part_u[base + 16 + tid],
                __float_as_uint(redB[0][tid] + redB[1][tid]),
                __ATOMIC_RELAXED, __HIP_MEMORY_SCOPE_SYSTEM);
            asm volatile("" :: "v"(o0), "v"(o1));
        }
        if (tid == 16) {
            unsigned int o2 = __hip_atomic_exchange(&part_u[base + 32],
                __float_as_uint(redV[0] + redV[1]),
                __ATOMIC_RELAXED, __HIP_MEMORY_SCOPE_SYSTEM);
            asm volatile("" :: "v"(o2));
        }
        asm volatile("s_waitcnt vmcnt(0)" ::: "memory");
        if (tid == 0) {
            (void)__hip_atomic_exchange(&flags[bid], MAGIC,
                __ATOMIC_RELAXED, __HIP_MEMORY_SCOPE_SYSTEM);
        }
        return;
    }

    // ---- block 0: statically-elected finisher (no uninitialized election
    //      state). Own contribution comes from LDS, not from slots.
    if (tid >= 1 && tid < NBLK) {
        int it = 0;
        unsigned int f;
        do {
            f = __hip_atomic_load(&flags[tid], __ATOMIC_RELAXED, __HIP_MEMORY_SCOPE_SYSTEM);
        } while (f != MAGIC && ++it < SPIN_BOUND);
    }
    __syncthreads();

    // System-scope loads bypass L1/L2 -> read the coherence point directly.
    for (int idx = tid; idx < (NBLK - 1) * SLOTS; idx += BLK) {
        int k = idx / SLOTS + 1;
        int j = idx % SLOTS;
        unsigned int u = __hip_atomic_load(&part_u[k * SLOTS + j],
                                           __ATOMIC_RELAXED, __HIP_MEMORY_SCOPE_SYSTEM);
        stage[idx] = __uint_as_float(u);
    }
    __syncthreads();

    const int j = tid;           // 0..127
    const int c = j >> 3;        // output bin j reads pooled column j/8
    float A = redA[0][c] + redA[1][c];
    float B = redB[0][c] + redB[1][c];
    float V = redV[0] + redV[1];
    for (int k = 1; k < NBLK; ++k) {
        A += stage[(k - 1) * SLOTS + c];
        B += stage[(k - 1) * SLOTS + 16 + c];
        V += stage[(k - 1) * SLOTS + 32];
    }
    out[j] = (A + V * B) / (float)SEQ;
}

extern "C" void kernel_launch(void* const* d_in, const int* in_sizes, int n_in,
                              void* d_out, int out_size, void* d_ws, size_t ws_size,
                              hipStream_t stream) {
    const float* x     = (const float*)d_in[0];
    const float* Wq    = (const float*)d_in[1];
    const float* bq    = (const float*)d_in[2];
    const float* Wk    = (const float*)d_in[3];
    const float* bk    = (const float*)d_in[4];
    const float* Wv    = (const float*)d_in[5];
    const float* bv    = (const float*)d_in[6];
    const int*   heads = (const int*)d_in[7];
    unsigned int* part_u = (unsigned int*)d_ws;                               // 64*33*4 = 8448 B
    unsigned int* flags  = (unsigned int*)((char*)d_ws + NBLK * SLOTS * sizeof(unsigned int)); // +256 B
    float*        out    = (float*)d_out;

    hipLaunchKernelGGL(satformer_fused, dim3(NBLK), dim3(BLK), 0, stream,
                       x, Wq, bq, Wk, bk, Wv, bv, heads, part_u, flags, out);
}

// Round 7
// 10.810 us; speedup vs baseline: 3.8957x; 1.5883x over previous
//
#include <hip/hip_runtime.h>
#include <math.h>

constexpr int SEQ = 8192;
constexpr int HID = 16;
constexpr int BLK = 256;            // threads per block (4 waves)
constexpr int NBLK = SEQ / BLK;     // 32 blocks
constexpr int SLOTS = 33;           // per-block partial: 16 A + 16 B + 1 Vtot
constexpr unsigned int MAGIC = 0x5EEDF00Du;
constexpr int SPIN_BOUND = 1 << 22;

__device__ __forceinline__ void load_row(const float* __restrict__ x, int r, float* f) {
    const float4* p = (const float4*)(x + (size_t)r * HID);
    float4 a = p[0], b = p[1], c = p[2], d = p[3];
    f[0]=a.x; f[1]=a.y; f[2]=a.z;  f[3]=a.w;
    f[4]=b.x; f[5]=b.y; f[6]=b.z;  f[7]=b.w;
    f[8]=c.x; f[9]=c.y; f[10]=c.z; f[11]=c.w;
    f[12]=d.x; f[13]=d.y; f[14]=d.z; f[15]=d.w;
}

__global__ __launch_bounds__(BLK) void satformer_fused(
    const float* __restrict__ x,
    const float* __restrict__ Wq, const float* __restrict__ bq,
    const float* __restrict__ Wk, const float* __restrict__ bk,
    const float* __restrict__ Wv, const float* __restrict__ bv,
    const int* __restrict__ heads_p,
    unsigned int* __restrict__ part_u,   // [NBLK*SLOTS] float bit-patterns (k=0 unused)
    unsigned int* __restrict__ flags,    // [NBLK] per-block done flags (k=0 unused)
    float* __restrict__ out)
{
    __shared__ float sWq[256];
    __shared__ float sWk[256];
    __shared__ alignas(16) float sM[16][16];   // M = Wq^T Wk (64B rows)
    __shared__ float su[16];      // u = Wq^T bk
    __shared__ float sw[16];      // w = Wk^T bq
    __shared__ float swv[16];     // column sums of Wv
    __shared__ float sbq[16];
    __shared__ float sbk[16];
    __shared__ float sc0;         // bq.bk
    __shared__ float sbv;         // sum of bv
    __shared__ alignas(16) float sX[BLK + 2][20];   // x rows, 80B-aligned rows
    __shared__ float sVr[BLK + 2];
    __shared__ float sG[BLK + 2];
    __shared__ float redA[4][16];
    __shared__ float redB[4][16];
    __shared__ float redV[4];
    __shared__ float stage[(NBLK - 1) * SLOTS + 1];   // block-0 only

    const int tid = threadIdx.x;
    const int bid = blockIdx.x;
    const int r0  = bid * BLK;
    const int s   = r0 + tid;

    // ---- phase 1: stage weights/biases -------------------------------------
    sWq[tid] = Wq[tid];           // BLK == 256 == HID*HID
    sWk[tid] = Wk[tid];
    if (tid < 16) {
        float acc = 0.f;
        #pragma unroll
        for (int d = 0; d < 16; ++d) acc += Wv[d * 16 + tid];
        swv[tid] = acc;
        sbq[tid] = bq[tid];
        sbk[tid] = bk[tid];
    }
    if (tid == BLK - 1) {
        float acc = 0.f;
        #pragma unroll
        for (int d = 0; d < 16; ++d) acc += bv[d];
        sbv = acc;
    }

    float xs[16];
    load_row(x, s, xs);
    __syncthreads();

    // ---- phase 2: M = Wq^T Wk, u, w, c0 ------------------------------------
    {
        int h1 = tid >> 4, h2 = tid & 15;
        float acc = 0.f;
        #pragma unroll
        for (int d = 0; d < 16; ++d) acc += sWq[d * 16 + h1] * sWk[d * 16 + h2];
        sM[h1][h2] = acc;
    }
    if (tid < 16) {
        float acc = 0.f;
        #pragma unroll
        for (int d = 0; d < 16; ++d) acc += sWq[d * 16 + tid] * sbk[d];
        su[tid] = acc;
    } else if (tid < 32) {
        int h = tid - 16;
        float acc = 0.f;
        #pragma unroll
        for (int d = 0; d < 16; ++d) acc += sWk[d * 16 + h] * sbq[d];
        sw[h] = acc;
    } else if (tid == 32) {
        float acc = 0.f;
        #pragma unroll
        for (int d = 0; d < 16; ++d) acc += sbq[d] * sbk[d];
        sc0 = acc;
    }
    __syncthreads();

    const float scaling = rsqrtf((float)(HID / heads_p[0]));   // heads=4 -> 0.5

    // ---- phase 3: per-row Vr, g, e, x->LDS, z = M^T x ----------------------
    float Vr = sbv, g = 0.f, e = 0.f;
    #pragma unroll
    for (int h = 0; h < 16; ++h) {
        Vr += xs[h] * swv[h];
        g  += xs[h] * sw[h];
        e  += xs[h] * su[h];
    }
    sVr[tid + 1] = Vr;
    sG[tid + 1]  = g;
    {
        float4* dst = (float4*)&sX[tid + 1][0];
        dst[0] = make_float4(xs[0],  xs[1],  xs[2],  xs[3]);
        dst[1] = make_float4(xs[4],  xs[5],  xs[6],  xs[7]);
        dst[2] = make_float4(xs[8],  xs[9],  xs[10], xs[11]);
        dst[3] = make_float4(xs[12], xs[13], xs[14], xs[15]);
    }
    float z[16];
    #pragma unroll
    for (int h = 0; h < 16; ++h) z[h] = 0.f;
    #pragma unroll
    for (int h1 = 0; h1 < 16; ++h1) {
        float xv = xs[h1];
        const float4* mrow = (const float4*)&sM[h1][0];
        float4 m0 = mrow[0], m1 = mrow[1], m2 = mrow[2], m3 = mrow[3];
        z[0]  += xv * m0.x; z[1]  += xv * m0.y; z[2]  += xv * m0.z; z[3]  += xv * m0.w;
        z[4]  += xv * m1.x; z[5]  += xv * m1.y; z[6]  += xv * m1.z; z[7]  += xv * m1.w;
        z[8]  += xv * m2.x; z[9]  += xv * m2.y; z[10] += xv * m2.z; z[11] += xv * m2.w;
        z[12] += xv * m3.x; z[13] += xv * m3.y; z[14] += xv * m3.z; z[15] += xv * m3.w;
    }

    // boundary rows r0-1 / r0+BLK by edge threads
    auto fillrow = [&](int row, int slot) {
        float xr[16];
        load_row(x, row, xr);
        float vr = sbv, gg = 0.f;
        #pragma unroll
        for (int h = 0; h < 16; ++h) { vr += xr[h] * swv[h]; gg += xr[h] * sw[h]; }
        sVr[slot] = vr;
        sG[slot]  = gg;
        float4* dst = (float4*)&sX[slot][0];
        dst[0] = make_float4(xr[0],  xr[1],  xr[2],  xr[3]);
        dst[1] = make_float4(xr[4],  xr[5],  xr[6],  xr[7]);
        dst[2] = make_float4(xr[8],  xr[9],  xr[10], xr[11]);
        dst[3] = make_float4(xr[12], xr[13], xr[14], xr[15]);
    };
    if (tid == 0 && r0 > 0)                 fillrow(r0 - 1, 0);
    if (tid == BLK - 1 && r0 + BLK < SEQ)   fillrow(r0 + BLK, BLK + 1);
    __syncthreads();

    // ---- phase 4: band scores + softmax partials ---------------------------
    // sc(s,j) = (z_s . x_j + u.x_s + w.x_j + bq.bk) * scaling  ==  (Q_s.K_j)*scaling
    float denom = 0.f, num = 0.f;
    int nb = 0;
    #pragma unroll
    for (int off = -1; off <= 1; ++off) {
        int j = s + off;
        if (j < 0 || j >= SEQ) continue;
        int li = tid + 1 + off;
        const float4* xr = (const float4*)&sX[li][0];
        float4 a0 = xr[0], a1 = xr[1], a2 = xr[2], a3 = xr[3];
        float dot = z[0]*a0.x + z[1]*a0.y + z[2]*a0.z + z[3]*a0.w
                  + z[4]*a1.x + z[5]*a1.y + z[6]*a1.z + z[7]*a1.w
                  + z[8]*a2.x + z[9]*a2.y + z[10]*a2.z + z[11]*a2.w
                  + z[12]*a3.x + z[13]*a3.y + z[14]*a3.z + z[15]*a3.w;
        float sc = (dot + e + sG[li] + sc0) * scaling;
        float ee = expf(sc);
        denom += ee;
        num   += (ee - 1.f) * sVr[li];
        ++nb;
    }
    denom += (float)(SEQ - nb);   // (S-nb) off-band exp(0)=1 terms

    float a = num / denom;
    float b = 1.f / denom;
    float v = sVr[tid + 1];

    // bucket c = s & 15 == tid & 15; xor-16/32 folds preserve the bucket
    float av = a, bb = b, vv = v;
    av += __shfl_xor(av, 16); av += __shfl_xor(av, 32);
    bb += __shfl_xor(bb, 16); bb += __shfl_xor(bb, 32);
    #pragma unroll
    for (int m = 1; m <= 32; m <<= 1) vv += __shfl_xor(vv, m);

    const int wave = tid >> 6;     // 0..3
    const int lane = tid & 63;
    if (lane < 16) { redA[wave][lane] = av; redB[wave][lane] = bb; }
    if (lane == 0) redV[wave] = vv;
    __syncthreads();

    if (bid != 0) {
        // ---- publish: system-scope exchanges, returns consumed, vmcnt(0),
        //      then flag. All publishers (tid<17) and the flag writer (tid 0)
        //      are in wave 0 — identical protocol to the round-6 pass.
        const int base = bid * SLOTS;
        if (tid < 16) {
            float sumA = redA[0][tid] + redA[1][tid] + redA[2][tid] + redA[3][tid];
            float sumB = redB[0][tid] + redB[1][tid] + redB[2][tid] + redB[3][tid];
            unsigned int o0 = __hip_atomic_exchange(&part_u[base + tid],
                __float_as_uint(sumA), __ATOMIC_RELAXED, __HIP_MEMORY_SCOPE_SYSTEM);
            unsigned int o1 = __hip_atomic_exchange(&part_u[base + 16 + tid],
                __float_as_uint(sumB), __ATOMIC_RELAXED, __HIP_MEMORY_SCOPE_SYSTEM);
            asm volatile("" :: "v"(o0), "v"(o1));
        }
        if (tid == 16) {
            float sumV = redV[0] + redV[1] + redV[2] + redV[3];
            unsigned int o2 = __hip_atomic_exchange(&part_u[base + 32],
                __float_as_uint(sumV), __ATOMIC_RELAXED, __HIP_MEMORY_SCOPE_SYSTEM);
            asm volatile("" :: "v"(o2));
        }
        asm volatile("s_waitcnt vmcnt(0)" ::: "memory");
        if (tid == 0) {
            (void)__hip_atomic_exchange(&flags[bid], MAGIC,
                __ATOMIC_RELAXED, __HIP_MEMORY_SCOPE_SYSTEM);
        }
        return;
    }

    // ---- block 0: statically-elected finisher ------------------------------
    if (tid >= 1 && tid < NBLK) {
        int it = 0;
        unsigned int f;
        do {
            f = __hip_atomic_load(&flags[tid], __ATOMIC_RELAXED, __HIP_MEMORY_SCOPE_SYSTEM);
        } while (f != MAGIC && ++it < SPIN_BOUND);
    }
    __syncthreads();

    // Batched slot read: (NBLK-1)*SLOTS = 1023 words at part_u[SLOTS + idx].
    // 4 independent system loads per thread -> one latency round, not 17.
    {
        const int i0 = tid, i1 = tid + 256, i2 = tid + 512, i3 = tid + 768;
        const int i3c = (i3 < (NBLK - 1) * SLOTS) ? i3 : 0;
        unsigned int u0 = __hip_atomic_load(&part_u[SLOTS + i0], __ATOMIC_RELAXED, __HIP_MEMORY_SCOPE_SYSTEM);
        unsigned int u1 = __hip_atomic_load(&part_u[SLOTS + i1], __ATOMIC_RELAXED, __HIP_MEMORY_SCOPE_SYSTEM);
        unsigned int u2 = __hip_atomic_load(&part_u[SLOTS + i2], __ATOMIC_RELAXED, __HIP_MEMORY_SCOPE_SYSTEM);
        unsigned int u3 = __hip_atomic_load(&part_u[SLOTS + i3c], __ATOMIC_RELAXED, __HIP_MEMORY_SCOPE_SYSTEM);
        stage[i0] = __uint_as_float(u0);
        stage[i1] = __uint_as_float(u1);
        stage[i2] = __uint_as_float(u2);
        if (i3 < (NBLK - 1) * SLOTS) stage[i3] = __uint_as_float(u3);
    }
    __syncthreads();

    if (tid < 128) {
        const int c = tid >> 3;        // output bin tid reads pooled column tid/8
        float A = redA[0][c] + redA[1][c] + redA[2][c] + redA[3][c];
        float B = redB[0][c] + redB[1][c] + redB[2][c] + redB[3][c];
        float V = redV[0] + redV[1] + redV[2] + redV[3];
        for (int k = 0; k < NBLK - 1; ++k) {
            A += stage[k * SLOTS + c];
            B += stage[k * SLOTS + 16 + c];
            V += stage[k * SLOTS + 32];
        }
        out[tid] = (A + V * B) / (float)SEQ;
    }
}

extern "C" void kernel_launch(void* const* d_in, const int* in_sizes, int n_in,
                              void* d_out, int out_size, void* d_ws, size_t ws_size,
                              hipStream_t stream) {
    const float* x     = (const float*)d_in[0];
    const float* Wq    = (const float*)d_in[1];
    const float* bq    = (const float*)d_in[2];
    const float* Wk    = (const float*)d_in[3];
    const float* bk    = (const float*)d_in[4];
    const float* Wv    = (const float*)d_in[5];
    const float* bv    = (const float*)d_in[6];
    const int*   heads = (const int*)d_in[7];
    unsigned int* part_u = (unsigned int*)d_ws;                               // 32*33*4 B
    unsigned int* flags  = (unsigned int*)((char*)d_ws + NBLK * SLOTS * sizeof(unsigned int));
    float*        out    = (float*)d_out;

    hipLaunchKernelGGL(satformer_fused, dim3(NBLK), dim3(BLK), 0, stream,
                       x, Wq, bq, Wk, bk, Wv, bv, heads, part_u, flags, out);
}